// Round 1
// baseline (411.724 us; speedup 1.0000x reference)
//
#include <hip/hip_runtime.h>
#include <math.h>

// Problem constants (fixed by the reference):
//   z_e: (B=64, D=64, H=32, W=32) fp32 ; codebook: (K=1024, 64) fp32
//   N = B*H*W = 65536 vectors of dim 64, HW = 1024
// Output layout (float32, concatenated in return order):
//   [0, 4194304)          z_q_st  (B,D,H,W)
//   [4194304]             vq_loss
//   [4194305]             commitment_loss
//   [4194306, 4259842)    encoding_indices (B,H,W) as float
//   [4259842]             codebook_usage
//   [4259843]             perplexity
//
// ws layout:
//   float ws_f[0..1024)     : cc[k] = |codebook_k|^2
//   uint  ws_u[1024..2048)  : histogram counts
//   float ws_f[2048..2304)  : per-block partial sums of (z_q - z_e)^2

#define N_VEC 65536
#define OFF_VQLOSS  4194304
#define OFF_COMMIT  4194305
#define OFF_IDX     4194306
#define OFF_USAGE   4259842
#define OFF_PERP    4259843

__global__ __launch_bounds__(256) void vq_init(const float* __restrict__ cb,
                                               float* __restrict__ ws_f,
                                               unsigned* __restrict__ ws_u) {
    int k = blockIdx.x * 256 + threadIdx.x;   // grid = 4 x 256 -> k in [0,1024)
    ws_u[1024 + k] = 0u;                       // zero histogram every launch
    const float* row = cb + k * 64;
    float acc = 0.0f;
    #pragma unroll
    for (int d = 0; d < 64; ++d) {
        float v = row[d];
        acc = __fadd_rn(acc, __fmul_rn(v, v)); // mul-then-add, mimic jnp.sum(c*c)
    }
    ws_f[k] = acc;
}

__global__ __launch_bounds__(256) void vq_main(const float* __restrict__ ze,
                                               const float* __restrict__ cb,
                                               const float* __restrict__ cc,
                                               unsigned* __restrict__ hist,
                                               float* __restrict__ partial,
                                               float* __restrict__ out) {
    const int n  = blockIdx.x * 256 + threadIdx.x;  // vector id = b*1024 + h*32 + w
    const int b  = n >> 10;
    const int hw = n & 1023;
    const size_t zbase = ((size_t)b << 16) + (size_t)hw; // element (b, d, h, w) at zbase + d*1024

    // z vector fully in VGPRs (coalesced per-d loads: lanes are consecutive hw)
    float z[64];
    #pragma unroll
    for (int d = 0; d < 64; ++d) z[d] = ze[zbase + ((size_t)d << 10)];

    // zz = sum z^2, fp32 mul-then-add like jnp.sum(z*z)
    float zz = 0.0f;
    #pragma unroll
    for (int d = 0; d < 64; ++d) zz = __fadd_rn(zz, __fmul_rn(z[d], z[d]));

    float best = INFINITY;
    int bestk = 0;
    // K loop: codebook row fetch is wave-uniform -> scalar loads from L2
    #pragma unroll 2
    for (int k = 0; k < 1024; ++k) {
        const float4* crow = reinterpret_cast<const float4*>(cb + (k << 6));
        float p[4] = {0.0f, 0.0f, 0.0f, 0.0f};
        #pragma unroll
        for (int j = 0; j < 16; ++j) {
            float4 c4 = crow[j];
            p[j & 3] = fmaf(z[4*j + 0], c4.x, p[j & 3]);
            p[j & 3] = fmaf(z[4*j + 1], c4.y, p[j & 3]);
            p[j & 3] = fmaf(z[4*j + 2], c4.z, p[j & 3]);
            p[j & 3] = fmaf(z[4*j + 3], c4.w, p[j & 3]);
        }
        float dot  = __fadd_rn(__fadd_rn(p[0], p[1]), __fadd_rn(p[2], p[3]));
        // dist = (zz + cc[k]) - 2*dot, rounding pinned to match the reference
        float dist = __fsub_rn(__fadd_rn(zz, cc[k]), __fmul_rn(2.0f, dot));
        if (dist < best) { best = dist; bestk = k; } // strict < == argmin first-occurrence
    }

    // Epilogue: gather chosen code, write z_q_st, local (z_q - z_e)^2 sum
    const float* qrow = cb + (bestk << 6);
    float sq = 0.0f;
    #pragma unroll
    for (int d = 0; d < 64; ++d) {
        float q = qrow[d];                         // divergent gather, L2-resident
        out[zbase + ((size_t)d << 10)] = q;        // z_q_st == z_q numerically
        float diff = __fsub_rn(q, z[d]);
        sq = __fadd_rn(sq, __fmul_rn(diff, diff));
    }
    out[OFF_IDX + n] = (float)bestk;
    atomicAdd(&hist[bestk], 1u);                   // integer atomic: deterministic

    // deterministic block reduction of sq
    #pragma unroll
    for (int off = 32; off > 0; off >>= 1) sq += __shfl_down(sq, off, 64);
    __shared__ float s_red[4];
    const int wid = threadIdx.x >> 6, lane = threadIdx.x & 63;
    if (lane == 0) s_red[wid] = sq;
    __syncthreads();
    if (threadIdx.x == 0)
        partial[blockIdx.x] = (s_red[0] + s_red[1]) + (s_red[2] + s_red[3]);
}

__global__ __launch_bounds__(256) void vq_fin(const float* __restrict__ partial,
                                              const unsigned* __restrict__ hist,
                                              float* __restrict__ out) {
    const int t = threadIdx.x;
    const int wid = t >> 6, lane = t & 63;
    __shared__ float s_loss[4], s_ent[4], s_nz[4];

    float v = partial[t];           // 256 block partials
    float ent = 0.0f, nz = 0.0f;
    #pragma unroll
    for (int i = 0; i < 4; ++i) {
        unsigned c = hist[t + 256 * i];
        float p = (float)c * (1.0f / 65536.0f);    // exact (pow2 divide)
        ent += p * logf(p + 1e-10f);               // c==0 -> 0 * log(1e-10) = 0
        if (c > 0u) nz += 1.0f;
    }
    #pragma unroll
    for (int off = 32; off > 0; off >>= 1) {
        v   += __shfl_down(v,   off, 64);
        ent += __shfl_down(ent, off, 64);
        nz  += __shfl_down(nz,  off, 64);
    }
    if (lane == 0) { s_loss[wid] = v; s_ent[wid] = ent; s_nz[wid] = nz; }
    __syncthreads();
    if (t == 0) {
        float S  = (s_loss[0] + s_loss[1]) + (s_loss[2] + s_loss[3]);
        float vq = S * (1.0f / 4194304.0f);        // mean over B*D*H*W
        out[OFF_VQLOSS] = vq;
        out[OFF_COMMIT] = 0.25f * vq;              // BETA * same mean
        float E  = (s_ent[0] + s_ent[1]) + (s_ent[2] + s_ent[3]);
        float NZ = (s_nz[0] + s_nz[1]) + (s_nz[2] + s_nz[3]);
        out[OFF_USAGE] = NZ * (1.0f / 1024.0f);
        out[OFF_PERP]  = expf(-E);
    }
}

extern "C" void kernel_launch(void* const* d_in, const int* in_sizes, int n_in,
                              void* d_out, int out_size, void* d_ws, size_t ws_size,
                              hipStream_t stream) {
    const float* ze = (const float*)d_in[0];
    const float* cb = (const float*)d_in[1];
    float*    out  = (float*)d_out;
    float*    ws_f = (float*)d_ws;
    unsigned* ws_u = (unsigned*)d_ws;

    vq_init<<<dim3(4),   dim3(256), 0, stream>>>(cb, ws_f, ws_u);
    vq_main<<<dim3(256), dim3(256), 0, stream>>>(ze, cb, ws_f, ws_u + 1024,
                                                 ws_f + 2048, out);
    vq_fin <<<dim3(1),   dim3(256), 0, stream>>>(ws_f + 2048, ws_u + 1024, out);
}

// Round 2
// 156.025 us; speedup vs baseline: 2.6388x; 2.6388x over previous
//
#include <hip/hip_runtime.h>
#include <math.h>

// Problem constants (fixed by the reference):
//   z_e: (B=64, D=64, H=32, W=32) fp32 ; codebook: (K=1024, 64) fp32
//   N = B*H*W = 65536 vectors of dim 64, HW = 1024
// Output layout (float32, concatenated in return order):
//   [0, 4194304)          z_q_st  (B,D,H,W)
//   [4194304]             vq_loss
//   [4194305]             commitment_loss
//   [4194306, 4259842)    encoding_indices (B,H,W) as float
//   [4259842]             codebook_usage
//   [4259843]             perplexity
//
// ws layout:
//   float ws_f[0..1024)     : cc[k] = |codebook_k|^2
//   uint  ws_u[1024..2048)  : histogram counts
//   float ws_f[2048..3072)  : per-block partial sums of (z_q - z_e)^2 (1024 blocks)

#define OFF_VQLOSS  4194304
#define OFF_COMMIT  4194305
#define OFF_IDX     4194306
#define OFF_USAGE   4259842
#define OFF_PERP    4259843

__global__ __launch_bounds__(256) void vq_init(const float* __restrict__ cb,
                                               float* __restrict__ ws_f,
                                               unsigned* __restrict__ ws_u) {
    int k = blockIdx.x * 256 + threadIdx.x;   // grid = 4 x 256 -> k in [0,1024)
    ws_u[1024 + k] = 0u;                       // zero histogram every launch
    const float* row = cb + k * 64;
    float acc = 0.0f;
    #pragma unroll
    for (int d = 0; d < 64; ++d) {
        float v = row[d];
        acc = __fadd_rn(acc, __fmul_rn(v, v)); // mul-then-add, mimic jnp.sum(c*c)
    }
    ws_f[k] = acc;
}

// Block = 256 threads = 4 waves; covers 64 vectors (one per lane).
// Wave w scans codebook quarter k in [w*256, (w+1)*256).
// launch_bounds(256,4): min 4 waves/EU -> VGPR cap 128, keeps z[64] resident
// (round-1 VGPR=52 proved the default heuristic spills z to scratch -> 505us).
__global__ __launch_bounds__(256, 4) void vq_main(const float* __restrict__ ze,
                                                  const float* __restrict__ cb,
                                                  const float* __restrict__ cc,
                                                  unsigned* __restrict__ hist,
                                                  float* __restrict__ partial,
                                                  float* __restrict__ out) {
    const int lane = threadIdx.x & 63;
    // readfirstlane: force wave-uniformity so codebook loads stay on the scalar pipe
    const int w = __builtin_amdgcn_readfirstlane(threadIdx.x >> 6);
    const int n  = blockIdx.x * 64 + lane;          // vector id = b*1024 + h*32 + w
    const int b  = n >> 10;
    const int hw = n & 1023;
    const size_t zbase = ((size_t)b << 16) + (size_t)hw; // (b,d,h,w) at zbase + d*1024

    // z vector fully in VGPRs (coalesced: lanes are consecutive hw)
    float z[64];
    #pragma unroll
    for (int d = 0; d < 64; ++d) z[d] = ze[zbase + ((size_t)d << 10)];

    // zz = sum z^2, fp32 mul-then-add like jnp.sum(z*z). Constant across k, so
    // its rounding shifts all distances equally -> argmin unaffected.
    float zz = 0.0f;
    #pragma unroll
    for (int d = 0; d < 64; ++d) zz = __fadd_rn(zz, __fmul_rn(z[d], z[d]));

    float best = INFINITY;
    int bestk = 0;
    const int k0 = w << 8;
    for (int kk = 0; kk < 256; ++kk) {
        const int k = k0 + kk;                       // wave-uniform -> s_load row
        const float4* crow = reinterpret_cast<const float4*>(cb + (k << 6));
        float p[4] = {0.0f, 0.0f, 0.0f, 0.0f};
        #pragma unroll
        for (int j = 0; j < 16; ++j) {
            float4 c4 = crow[j];
            p[j & 3] = fmaf(z[4*j + 0], c4.x, p[j & 3]);
            p[j & 3] = fmaf(z[4*j + 1], c4.y, p[j & 3]);
            p[j & 3] = fmaf(z[4*j + 2], c4.z, p[j & 3]);
            p[j & 3] = fmaf(z[4*j + 3], c4.w, p[j & 3]);
        }
        float dot  = __fadd_rn(__fadd_rn(p[0], p[1]), __fadd_rn(p[2], p[3]));
        // dist = (zz + cc[k]) - 2*dot  (bit-identical to round-1 kernel)
        float dist = __fsub_rn(__fadd_rn(zz, cc[k]), __fmul_rn(2.0f, dot));
        if (dist < best) { best = dist; bestk = k; } // strict < == first-occurrence
    }

    // Cross-wave argmin combine. k ranges ascend with w, so strict < keeps the
    // lowest-k winner on exact ties, matching jnp.argmin.
    __shared__ float s_best[3][64];
    __shared__ int   s_bk[3][64];
    if (w > 0) { s_best[w - 1][lane] = best; s_bk[w - 1][lane] = bestk; }
    __syncthreads();

    if (w == 0) {
        #pragma unroll
        for (int i = 0; i < 3; ++i) {
            float b2 = s_best[i][lane];
            int   k2 = s_bk[i][lane];
            if (b2 < best) { best = b2; bestk = k2; }
        }

        // Epilogue: gather chosen code, write z_q_st, local (z_q - z_e)^2 sum
        const float4* qrow = reinterpret_cast<const float4*>(cb + (bestk << 6));
        float sq = 0.0f;
        #pragma unroll
        for (int j = 0; j < 16; ++j) {
            float4 q4 = qrow[j];                   // divergent gather, L2-resident
            const float q[4] = {q4.x, q4.y, q4.z, q4.w};
            #pragma unroll
            for (int e = 0; e < 4; ++e) {
                int d = 4*j + e;
                out[zbase + ((size_t)d << 10)] = q[e];   // z_q_st == z_q numerically
                float diff = __fsub_rn(q[e], z[d]);
                sq = __fadd_rn(sq, __fmul_rn(diff, diff));
            }
        }
        out[OFF_IDX + n] = (float)bestk;
        atomicAdd(&hist[bestk], 1u);               // integer atomic: deterministic

        // deterministic wave-0 reduction of sq -> one partial per block
        #pragma unroll
        for (int off = 32; off > 0; off >>= 1) sq += __shfl_down(sq, off, 64);
        if (lane == 0) partial[blockIdx.x] = sq;
    }
}

__global__ __launch_bounds__(256) void vq_fin(const float* __restrict__ partial,
                                              const unsigned* __restrict__ hist,
                                              float* __restrict__ out) {
    const int t = threadIdx.x;
    const int wid = t >> 6, lane = t & 63;
    __shared__ float s_loss[4], s_ent[4], s_nz[4];

    float v = 0.0f, ent = 0.0f, nz = 0.0f;
    #pragma unroll
    for (int i = 0; i < 4; ++i) {
        v += partial[t + 256 * i];                 // 1024 block partials
        unsigned c = hist[t + 256 * i];
        float p = (float)c * (1.0f / 65536.0f);    // exact (pow2 divide)
        ent += p * logf(p + 1e-10f);               // c==0 -> 0 * log(1e-10) = 0
        if (c > 0u) nz += 1.0f;
    }
    #pragma unroll
    for (int off = 32; off > 0; off >>= 1) {
        v   += __shfl_down(v,   off, 64);
        ent += __shfl_down(ent, off, 64);
        nz  += __shfl_down(nz,  off, 64);
    }
    if (lane == 0) { s_loss[wid] = v; s_ent[wid] = ent; s_nz[wid] = nz; }
    __syncthreads();
    if (t == 0) {
        float S  = (s_loss[0] + s_loss[1]) + (s_loss[2] + s_loss[3]);
        float vq = S * (1.0f / 4194304.0f);        // mean over B*D*H*W
        out[OFF_VQLOSS] = vq;
        out[OFF_COMMIT] = 0.25f * vq;              // BETA * same mean
        float E  = (s_ent[0] + s_ent[1]) + (s_ent[2] + s_ent[3]);
        float NZ = (s_nz[0] + s_nz[1]) + (s_nz[2] + s_nz[3]);
        out[OFF_USAGE] = NZ * (1.0f / 1024.0f);
        out[OFF_PERP]  = expf(-E);
    }
}

extern "C" void kernel_launch(void* const* d_in, const int* in_sizes, int n_in,
                              void* d_out, int out_size, void* d_ws, size_t ws_size,
                              hipStream_t stream) {
    const float* ze = (const float*)d_in[0];
    const float* cb = (const float*)d_in[1];
    float*    out  = (float*)d_out;
    float*    ws_f = (float*)d_ws;
    unsigned* ws_u = (unsigned*)d_ws;

    vq_init<<<dim3(4),    dim3(256), 0, stream>>>(cb, ws_f, ws_u);
    vq_main<<<dim3(1024), dim3(256), 0, stream>>>(ze, cb, ws_f, ws_u + 1024,
                                                  ws_f + 2048, out);
    vq_fin <<<dim3(1),    dim3(256), 0, stream>>>(ws_f + 2048, ws_u + 1024, out);
}

// Round 3
// 151.560 us; speedup vs baseline: 2.7166x; 1.0295x over previous
//
#include <hip/hip_runtime.h>
#include <math.h>

// Problem constants (fixed by the reference):
//   z_e: (B=64, D=64, H=32, W=32) fp32 ; codebook: (K=1024, 64) fp32
//   N = B*H*W = 65536 vectors of dim 64, HW = 1024
// Output layout (float32, concatenated in return order):
//   [0, 4194304)          z_q_st  (B,D,H,W)
//   [4194304]             vq_loss
//   [4194305]             commitment_loss
//   [4194306, 4259842)    encoding_indices (B,H,W) as float
//   [4259842]             codebook_usage
//   [4259843]             perplexity
//
// ws layout:
//   float ws_f[0..1024)     : cc[k] = |codebook_k|^2
//   uint  ws_u[1024..2048)  : histogram counts
//   float ws_f[2048..3072)  : per-block partial sums of (z_q - z_e)^2 (1024 blocks)

#define OFF_VQLOSS  4194304
#define OFF_COMMIT  4194305
#define OFF_IDX     4194306
#define OFF_USAGE   4259842
#define OFF_PERP    4259843

__global__ __launch_bounds__(256) void vq_init(const float* __restrict__ cb,
                                               float* __restrict__ ws_f,
                                               unsigned* __restrict__ ws_u) {
    int k = blockIdx.x * 256 + threadIdx.x;   // grid = 4 x 256 -> k in [0,1024)
    ws_u[1024 + k] = 0u;                       // zero histogram every launch
    const float* row = cb + k * 64;
    float acc = 0.0f;
    #pragma unroll
    for (int d = 0; d < 64; ++d) {
        float v = row[d];
        acc = __fadd_rn(acc, __fmul_rn(v, v)); // mul-then-add, mimic jnp.sum(c*c)
    }
    ws_f[k] = acc;
}

// Block = 512 threads = 8 waves; covers 64 vectors (one per lane).
// Wave w scans codebook eighth k in [w*128, (w+1)*128).
// Round-2 evidence: VGPR=52 with perf scaling exactly with occupancy ->
// compiler remat'd the z loads into the k-loop. Fixes here:
//  (a) asm pin on z[d] blocks the remat (VGPR should rise to ~105),
//  (b) 8 waves/block doubles resident waves if the compiler stays low-VGPR.
__global__ __launch_bounds__(512, 4) void vq_main(const float* __restrict__ ze,
                                                  const float* __restrict__ cb,
                                                  const float* __restrict__ cc,
                                                  unsigned* __restrict__ hist,
                                                  float* __restrict__ partial,
                                                  float* __restrict__ out) {
    const int lane = threadIdx.x & 63;
    // readfirstlane: force wave-uniformity so codebook loads stay on the scalar pipe
    const int w = __builtin_amdgcn_readfirstlane(threadIdx.x >> 6); // 0..7
    const int n  = blockIdx.x * 64 + lane;          // vector id = b*1024 + h*32 + w
    const int b  = n >> 10;
    const int hw = n & 1023;
    const size_t zbase = ((size_t)b << 16) + (size_t)hw; // (b,d,h,w) at zbase + d*1024

    // z vector in VGPRs (coalesced: lanes are consecutive hw)
    float z[64];
    #pragma unroll
    for (int d = 0; d < 64; ++d) z[d] = ze[zbase + ((size_t)d << 10)];
    // Pin: make each z[d] opaque so the loads cannot be sunk/remat'd into the
    // k-loop (round-2 pathology). Keeps z register-resident.
    #pragma unroll
    for (int d = 0; d < 64; ++d) asm volatile("" : "+v"(z[d]));

    // zz = sum z^2, fp32 mul-then-add like jnp.sum(z*z). Constant across k, so
    // its rounding shifts all distances equally -> argmin unaffected.
    float zz = 0.0f;
    #pragma unroll
    for (int d = 0; d < 64; ++d) zz = __fadd_rn(zz, __fmul_rn(z[d], z[d]));

    float best = INFINITY;
    int bestk = 0;
    const int k0 = w << 7;
    for (int kk = 0; kk < 128; ++kk) {
        const int k = k0 + kk;                       // wave-uniform -> s_load row
        const float4* crow = reinterpret_cast<const float4*>(cb + (k << 6));
        float p[4] = {0.0f, 0.0f, 0.0f, 0.0f};
        #pragma unroll
        for (int j = 0; j < 16; ++j) {
            float4 c4 = crow[j];
            p[j & 3] = fmaf(z[4*j + 0], c4.x, p[j & 3]);
            p[j & 3] = fmaf(z[4*j + 1], c4.y, p[j & 3]);
            p[j & 3] = fmaf(z[4*j + 2], c4.z, p[j & 3]);
            p[j & 3] = fmaf(z[4*j + 3], c4.w, p[j & 3]);
        }
        float dot  = __fadd_rn(__fadd_rn(p[0], p[1]), __fadd_rn(p[2], p[3]));
        // dist = (zz + cc[k]) - 2*dot  (bit-identical to round-1/2 kernels)
        float dist = __fsub_rn(__fadd_rn(zz, cc[k]), __fmul_rn(2.0f, dot));
        if (dist < best) { best = dist; bestk = k; } // strict < == first-occurrence
    }

    // Cross-wave argmin combine. k ranges ascend with w, so strict < keeps the
    // lowest-k winner on exact ties, matching jnp.argmin.
    __shared__ float s_best[7][64];
    __shared__ int   s_bk[7][64];
    if (w > 0) { s_best[w - 1][lane] = best; s_bk[w - 1][lane] = bestk; }
    __syncthreads();

    if (w == 0) {
        #pragma unroll
        for (int i = 0; i < 7; ++i) {
            float b2 = s_best[i][lane];
            int   k2 = s_bk[i][lane];
            if (b2 < best) { best = b2; bestk = k2; }
        }

        // Epilogue: gather chosen code, write z_q_st, local (z_q - z_e)^2 sum
        const float4* qrow = reinterpret_cast<const float4*>(cb + (bestk << 6));
        float sq = 0.0f;
        #pragma unroll
        for (int j = 0; j < 16; ++j) {
            float4 q4 = qrow[j];                   // divergent gather, L2-resident
            const float q[4] = {q4.x, q4.y, q4.z, q4.w};
            #pragma unroll
            for (int e = 0; e < 4; ++e) {
                int d = 4*j + e;
                out[zbase + ((size_t)d << 10)] = q[e];   // z_q_st == z_q numerically
                float diff = __fsub_rn(q[e], z[d]);
                sq = __fadd_rn(sq, __fmul_rn(diff, diff));
            }
        }
        out[OFF_IDX + n] = (float)bestk;
        atomicAdd(&hist[bestk], 1u);               // integer atomic: deterministic

        // deterministic wave-0 reduction of sq -> one partial per block
        #pragma unroll
        for (int off = 32; off > 0; off >>= 1) sq += __shfl_down(sq, off, 64);
        if (lane == 0) partial[blockIdx.x] = sq;
    }
}

__global__ __launch_bounds__(256) void vq_fin(const float* __restrict__ partial,
                                              const unsigned* __restrict__ hist,
                                              float* __restrict__ out) {
    const int t = threadIdx.x;
    const int wid = t >> 6, lane = t & 63;
    __shared__ float s_loss[4], s_ent[4], s_nz[4];

    float v = 0.0f, ent = 0.0f, nz = 0.0f;
    #pragma unroll
    for (int i = 0; i < 4; ++i) {
        v += partial[t + 256 * i];                 // 1024 block partials
        unsigned c = hist[t + 256 * i];
        float p = (float)c * (1.0f / 65536.0f);    // exact (pow2 divide)
        ent += p * logf(p + 1e-10f);               // c==0 -> 0 * log(1e-10) = 0
        if (c > 0u) nz += 1.0f;
    }
    #pragma unroll
    for (int off = 32; off > 0; off >>= 1) {
        v   += __shfl_down(v,   off, 64);
        ent += __shfl_down(ent, off, 64);
        nz  += __shfl_down(nz,  off, 64);
    }
    if (lane == 0) { s_loss[wid] = v; s_ent[wid] = ent; s_nz[wid] = nz; }
    __syncthreads();
    if (t == 0) {
        float S  = (s_loss[0] + s_loss[1]) + (s_loss[2] + s_loss[3]);
        float vq = S * (1.0f / 4194304.0f);        // mean over B*D*H*W
        out[OFF_VQLOSS] = vq;
        out[OFF_COMMIT] = 0.25f * vq;              // BETA * same mean
        float E  = (s_ent[0] + s_ent[1]) + (s_ent[2] + s_ent[3]);
        float NZ = (s_nz[0] + s_nz[1]) + (s_nz[2] + s_nz[3]);
        out[OFF_USAGE] = NZ * (1.0f / 1024.0f);
        out[OFF_PERP]  = expf(-E);
    }
}

extern "C" void kernel_launch(void* const* d_in, const int* in_sizes, int n_in,
                              void* d_out, int out_size, void* d_ws, size_t ws_size,
                              hipStream_t stream) {
    const float* ze = (const float*)d_in[0];
    const float* cb = (const float*)d_in[1];
    float*    out  = (float*)d_out;
    float*    ws_f = (float*)d_ws;
    unsigned* ws_u = (unsigned*)d_ws;

    vq_init<<<dim3(4),    dim3(256), 0, stream>>>(cb, ws_f, ws_u);
    vq_main<<<dim3(1024), dim3(512), 0, stream>>>(ze, cb, ws_f, ws_u + 1024,
                                                  ws_f + 2048, out);
    vq_fin <<<dim3(1),    dim3(256), 0, stream>>>(ws_f + 2048, ws_u + 1024, out);
}